// Round 14
// baseline (132.151 us; speedup 1.0000x reference)
//
#include <hip/hip_runtime.h>
#include <hip/hip_bf16.h>

#define B_   8
#define N_   512
#define IND  256
#define H_   4
#define PH   32
#define OD   128   // H_*PH
#define TI   4     // targets per block (attn)

typedef float v2f __attribute__((ext_vector_type(2)));

// leaky 0.4 * log2(e), and 0.6 * log2(e): logits in log2 domain -> v_exp_f32.
#define ATT_SCALE 0.5770780163555854f
#define DLR_SCALE 0.8656170245333781f

template <int PAT>
__device__ __forceinline__ float dpp_add(float x) {
    int yi = __builtin_amdgcn_mov_dpp(__float_as_int(x), PAT, 0xF, 0xF, true);
    return x + __int_as_float(yi);
}

__device__ __forceinline__ float fast_exp2(float x) {
#if __has_builtin(__builtin_amdgcn_exp2f)
    return __builtin_amdgcn_exp2f(x);
#else
    return exp2f(x);
#endif
}

// Packed fp32 FMA / ADD forced as single VOP3P instructions (r9 post-mortem).
__device__ __forceinline__ void pk_fma(v2f& d, v2f a, v2f b) {
    asm("v_pk_fma_f32 %0, %1, %2, %0" : "+v"(d) : "v"(a), "v"(b));
}
__device__ __forceinline__ v2f pk_add(v2f a, v2f b) {
    v2f d;
    asm("v_pk_add_f32 %0, %1, %2" : "=v"(d) : "v"(a), "v"(b));
    return d;
}

// ---------------------------------------------------------------------------
// Kernel 0: pack adjacency into j-CONTIGUOUS nibble table, diagonal folded.
// packT[(b*128 + iq)*512 + j] = 4 mask bits for targets i = iq*4..iq*4+3.
// r13 post-mortem: the old [j][dword] layout cost 16 cache-line segments
// per u in attn; j-contiguous bytes cost 1.
// grid 1024, block 256: wave packs row (b,j) via 8 ballots; lanes 0-15 of
// each ballot scatter the 16 nibbles to their iq planes.
// ---------------------------------------------------------------------------
__global__ __launch_bounds__(256) void pack_kernel(
    const int* __restrict__ adj, unsigned char* __restrict__ packT)
{
    const int t = threadIdx.x;
    const int lane = t & 63;
    const int r = blockIdx.x * 4 + (t >> 6);     // (b*N + j)
    const int j = r & (N_ - 1);
    const int b = r >> 9;
    const int* row = adj + (size_t)r * N_;
    #pragma unroll
    for (int k = 0; k < 8; ++k) {
        const int i = k * 64 + lane;
        int a = row[i];
        unsigned long long m = __ballot(a != 0 || i == j);
        if (lane < 16) {
            const int iq = k * 16 + lane;
            packT[((size_t)(b * 128 + iq)) * N_ + j] =
                (unsigned char)((m >> (lane * 4)) & 15ull);
        }
    }
}

// ---------------------------------------------------------------------------
// Kernel 1: xl = x@Wl + bl ; xr = x@Wr + br  plus pre-scaled rank-1 parts,
// stored TRANSPOSED: dlT/drT[(b*H + h)*N + n]  (j-contiguous for attn).
// grid 512, block 256; 8 rows per block. (structure proven r5-r13)
// ---------------------------------------------------------------------------
__global__ __launch_bounds__(256, 2) void proj_kernel(
    const float* __restrict__ x,
    const float* __restrict__ Wl, const float* __restrict__ bl,
    const float* __restrict__ Wr, const float* __restrict__ br,
    const float* __restrict__ att,
    float* __restrict__ xl, float* __restrict__ xr,
    float* __restrict__ dlT, float* __restrict__ drT)
{
    __shared__ float xs[8 * IND];
    const int t = threadIdx.x;
    const int row0 = blockIdx.x * 8;

    const float4* xp4 = (const float4*)(x + (size_t)row0 * IND);
    float4* xs4 = (float4*)xs;
    #pragma unroll
    for (int k = 0; k < 2; ++k)
        xs4[t + k * 256] = xp4[t + k * 256];
    __syncthreads();

    const int which = t >> 7;
    const int rg = (t >> 6) & 1;
    const int og = t & 63;
    const int o0 = og * 2;
    const int r0 = rg * 4;
    const float* W  = which ? Wr : Wl;
    const float* bb = which ? br : bl;

    float acc0[4], acc1[4];
    #pragma unroll
    for (int r = 0; r < 4; ++r) { acc0[r] = 0.f; acc1[r] = 0.f; }

    for (int k = 0; k < IND; k += 4) {
        float wf0[4], wf1[4];
        #pragma unroll
        for (int kk = 0; kk < 4; ++kk) {
            float2 wv = *(const float2*)(W + (size_t)(k + kk) * OD + o0);
            wf0[kk] = wv.x;
            wf1[kk] = wv.y;
        }
        float xv[4][4];
        #pragma unroll
        for (int r = 0; r < 4; ++r)
            *(float4*)(xv[r]) = *(const float4*)(&xs[(r0 + r) * IND + k]);
        #pragma unroll
        for (int kk = 0; kk < 4; ++kk)
            #pragma unroll
            for (int r = 0; r < 4; ++r) {
                acc0[r] = fmaf(xv[r][kk], wf0[kk], acc0[r]);
                acc1[r] = fmaf(xv[r][kk], wf1[kk], acc1[r]);
            }
    }

    const float bv0 = bb[o0];
    const float bv1 = bb[o0 + 1];
    const float a0 = att[o0];
    const float a1 = att[o0 + 1];
    float* dst = which ? xr : xl;
    float* dp  = which ? drT : dlT;
    float dcon[4];
    #pragma unroll
    for (int r = 0; r < 4; ++r) {
        float y0 = acc0[r] + bv0;
        float y1 = acc1[r] + bv1;
        *(float2*)(&dst[(size_t)(row0 + r0 + r) * OD + o0]) = make_float2(y0, y1);
        dcon[r] = fmaf(a0, y0, a1 * y1);
    }
    #pragma unroll
    for (int m = 1; m < 16; m <<= 1) {
        #pragma unroll
        for (int r = 0; r < 4; ++r)
            dcon[r] += __shfl_xor(dcon[r], m);
    }
    if ((og & 15) == 0) {
        const int h = og >> 4;
        #pragma unroll
        for (int r = 0; r < 4; ++r) {
            const int n = row0 + r0 + r;
            const int bb2 = n >> 9, nn = n & (N_ - 1);
            dp[((size_t)(bb2 * H_ + h)) * N_ + nn] = DLR_SCALE * dcon[r];
        }
    }
}

// ---------------------------------------------------------------------------
// Kernel 2: masked-softmax attention, j-SPLIT 2-way. ZERO LDS, ZERO BARRIERS.
// grid 2048 (= 2 splits x B*N/TI interleaved), block 256 -> 8 blocks/CU,
// 32 waves/CU at VGPR<=64: lets VALU (~13us/CU) and TA (~7us/CU) overlap
// (r13 post-mortem: 4 blocks/CU gave poor cross-pipe overlap -> 42us).
// thread: cq = t&3, js = (t>>2)&15, h = t>>6. Each block covers 256 j's.
// Mask: 1-byte j-contiguous nibble load (1 segment/u); dl: j-contiguous
// (1 segment/u). Partial acc/sumw written to ws; combine_kernel finishes.
// ---------------------------------------------------------------------------
__global__ __launch_bounds__(256, 3) void attn_kernel(
    const unsigned char* __restrict__ packT,
    const float* __restrict__ att,
    const float* __restrict__ xl, const float* __restrict__ xr,
    const float* __restrict__ dlT, const float* __restrict__ drT,
    float* __restrict__ pacc, float* __restrict__ psum)
{
    const int t = threadIdx.x;
    const int s   = blockIdx.x & 1;
    const int blk = blockIdx.x >> 1;
    const int b  = blk >> 7;
    const int i0 = (blk & 127) * TI;
    const int cq = t & 3;
    const int js = (t >> 2) & 15;
    const int h  = t >> 6;
    const int cbase = h * PH + cq * 8;
    const int j0 = s * 256;

    float atS[8];
    {
        const float* ap = att + cbase;
        float4 a0 = *(const float4*)(ap);
        float4 a1 = *(const float4*)(ap + 4);
        atS[0] = ATT_SCALE * a0.x; atS[1] = ATT_SCALE * a0.y;
        atS[2] = ATT_SCALE * a0.z; atS[3] = ATT_SCALE * a0.w;
        atS[4] = ATT_SCALE * a1.x; atS[5] = ATT_SCALE * a1.y;
        atS[6] = ATT_SCALE * a1.z; atS[7] = ATT_SCALE * a1.w;
    }
    v2f xr2[TI][4];
    float drv[TI];
    #pragma unroll
    for (int il = 0; il < TI; ++il) {
        const float* xp = xr + ((size_t)(b * N_ + i0 + il)) * OD + cbase;
        float4 r0 = *(const float4*)(xp);
        float4 r1 = *(const float4*)(xp + 4);
        xr2[il][0] = (v2f){r0.x, r0.y};
        xr2[il][1] = (v2f){r0.z, r0.w};
        xr2[il][2] = (v2f){r1.x, r1.y};
        xr2[il][3] = (v2f){r1.z, r1.w};
        drv[il] = drT[((size_t)(b * H_ + h)) * N_ + i0 + il];  // pre-scaled
    }

    v2f acc[TI][4];
    float sumw[TI];
    #pragma unroll
    for (int il = 0; il < TI; ++il) {
        sumw[il] = 0.f;
        #pragma unroll
        for (int m = 0; m < 4; ++m) acc[il][m] = (v2f){0.f, 0.f};
    }

    // software-pipelined j-loop: j = j0 + u*16 + js, u = 0..15
    const float*         xlp = xl + ((size_t)(b * N_ + j0 + js)) * OD + cbase;
    const unsigned char* ptp = packT + ((size_t)(b * 128 + (i0 >> 2))) * N_ + j0 + js;
    const float*         dlp = dlT + ((size_t)(b * H_ + h)) * N_ + j0 + js;

    float4   va = *(const float4*)(xlp);
    float4   vb = *(const float4*)(xlp + 4);
    unsigned pj = *ptp;
    float    dj = *dlp;

    #pragma unroll 2
    for (int u = 0; u < 16; ++u) {
        float4   wa = va, wb = vb;
        unsigned wp = pj;
        float    wd = dj;
        if (u < 15) {
            xlp += 16 * OD; ptp += 16; dlp += 16;
            va = *(const float4*)(xlp);
            vb = *(const float4*)(xlp + 4);
            pj = *ptp;
            dj = *dlp;
        }
        v2f p0 = (v2f){wa.x, wa.y}, p1 = (v2f){wa.z, wa.w};
        v2f p2 = (v2f){wb.x, wb.y}, p3 = (v2f){wb.z, wb.w};
        #pragma unroll
        for (int il = 0; il < TI; ++il) {
            float e2a = 0.f, e2b = 0.f;
            v2f sv;
            sv = pk_add(xr2[il][0], p0);
            e2a = fmaf(atS[0], __builtin_fabsf(sv.x), e2a);
            e2b = fmaf(atS[1], __builtin_fabsf(sv.y), e2b);
            sv = pk_add(xr2[il][1], p1);
            e2a = fmaf(atS[2], __builtin_fabsf(sv.x), e2a);
            e2b = fmaf(atS[3], __builtin_fabsf(sv.y), e2b);
            sv = pk_add(xr2[il][2], p2);
            e2a = fmaf(atS[4], __builtin_fabsf(sv.x), e2a);
            e2b = fmaf(atS[5], __builtin_fabsf(sv.y), e2b);
            sv = pk_add(xr2[il][3], p3);
            e2a = fmaf(atS[6], __builtin_fabsf(sv.x), e2a);
            e2b = fmaf(atS[7], __builtin_fabsf(sv.y), e2b);
            float eh = e2a + e2b;
            eh = dpp_add<0xB1>(eh);          // + lane^1 (quad_perm 1,0,3,2)
            eh = dpp_add<0x4E>(eh);          // + lane^2 (quad_perm 2,3,0,1)
            float e = (wd + drv[il]) + eh;   // full log2-domain logit
            float ex = fast_exp2(e);
            float w = (wp & (1u << il)) ? ex : 0.f;   // diagonal pre-folded
            sumw[il] += w;
            v2f ws = (v2f){w, w};
            pk_fma(acc[il][0], ws, p0);
            pk_fma(acc[il][1], ws, p1);
            pk_fma(acc[il][2], ws, p2);
            pk_fma(acc[il][3], ws, p3);
        }
    }

    // ---- epilogue: pure-shuffle reduce-scatter over js (lane bits 2-5) ----
    #pragma unroll
    for (int il = 0; il < TI; ++il) {
        sumw[il] += __shfl_xor(sumw[il], 4);
        sumw[il] += __shfl_xor(sumw[il], 8);
        sumw[il] += __shfl_xor(sumw[il], 16);
        sumw[il] += __shfl_xor(sumw[il], 32);
    }

    float accf[32];
    #pragma unroll
    for (int il = 0; il < TI; ++il)
        #pragma unroll
        for (int m = 0; m < 4; ++m) {
            accf[il * 8 + 2 * m]     = acc[il][m].x;
            accf[il * 8 + 2 * m + 1] = acc[il][m].y;
        }

    float r16[16];
    {
        const bool hi = (js & 1) != 0;
        #pragma unroll
        for (int m = 0; m < 16; ++m) {
            float send = hi ? accf[m] : accf[16 + m];
            float keep = hi ? accf[16 + m] : accf[m];
            r16[m] = keep + __shfl_xor(send, 4);
        }
    }
    float r8[8];
    {
        const bool hi = (js & 2) != 0;
        #pragma unroll
        for (int m = 0; m < 8; ++m) {
            float send = hi ? r16[m] : r16[8 + m];
            float keep = hi ? r16[8 + m] : r16[m];
            r8[m] = keep + __shfl_xor(send, 8);
        }
    }
    float r4[4];
    {
        const bool hi = (js & 4) != 0;
        #pragma unroll
        for (int m = 0; m < 4; ++m) {
            float send = hi ? r8[m] : r8[4 + m];
            float keep = hi ? r8[4 + m] : r8[m];
            r4[m] = keep + __shfl_xor(send, 16);
        }
    }
    float r2[2];
    {
        const bool hi = (js & 8) != 0;
        #pragma unroll
        for (int m = 0; m < 2; ++m) {
            float send = hi ? r4[m] : r4[2 + m];
            float keep = hi ? r4[2 + m] : r4[m];
            r2[m] = keep + __shfl_xor(send, 32);
        }
    }

    const int il = ((js & 1) << 1) | ((js >> 1) & 1);
    const int coff = ((js >> 2) & 1) * 4 + ((js >> 3) & 1) * 2;
    const int c = cbase + coff;
    float* pa = pacc + (size_t)s * (B_ * N_ * OD)
                     + ((size_t)(b * N_ + i0 + il)) * OD + c;
    *(float2*)pa = make_float2(r2[0], r2[1]);
    if ((t & 63) == 0) {
        float* ps = psum + s * (B_ * N_ * H_);
        #pragma unroll
        for (int q = 0; q < TI; ++q)
            ps[(size_t)(b * N_ + i0 + q) * H_ + h] = sumw[q];
    }
}

// ---------------------------------------------------------------------------
// Kernel 3: combine the 2 j-split partials: out = (a0+a1)/(s0+s1) + bias.
// grid 1024, block 256; one float2 per thread. ~6 MB traffic, ~2 us.
// ---------------------------------------------------------------------------
__global__ __launch_bounds__(256) void combine_kernel(
    const float* __restrict__ pacc, const float* __restrict__ psum,
    const float* __restrict__ bias, float* __restrict__ out)
{
    const int idx = blockIdx.x * 256 + threadIdx.x;   // 0..262143
    const int n = idx >> 6;
    const int c = (idx & 63) * 2;
    const int h = c >> 5;
    float2 a0 = *(const float2*)(pacc + (size_t)n * OD + c);
    float2 a1 = *(const float2*)(pacc + (size_t)B_ * N_ * OD + (size_t)n * OD + c);
    float sden = psum[(size_t)n * H_ + h] + psum[B_ * N_ * H_ + (size_t)n * H_ + h];
    float inv = 1.f / sden;
    *(float2*)(out + (size_t)n * OD + c) =
        make_float2(fmaf(a0.x + a1.x, inv, bias[c]),
                    fmaf(a0.y + a1.y, inv, bias[c + 1]));
}

extern "C" void kernel_launch(void* const* d_in, const int* in_sizes, int n_in,
                              void* d_out, int out_size, void* d_ws, size_t ws_size,
                              hipStream_t stream) {
    const float* x    = (const float*)d_in[0];
    const int*   adj  = (const int*)d_in[1];
    const float* Wl   = (const float*)d_in[2];
    const float* bl   = (const float*)d_in[3];
    const float* Wr   = (const float*)d_in[4];
    const float* br   = (const float*)d_in[5];
    const float* att  = (const float*)d_in[6];
    const float* bias = (const float*)d_in[7];
    float* out = (float*)d_out;

    float* ws = (float*)d_ws;
    float* xl   = ws;                                   // 524288 f
    float* xr   = xl + (size_t)B_ * N_ * OD;            // 524288 f
    float* dlT  = xr + (size_t)B_ * N_ * OD;            // 16384 f
    float* drT  = dlT + (size_t)B_ * N_ * H_;           // 16384 f
    float* pacc = drT + (size_t)B_ * N_ * H_;           // 2*524288 f
    float* psum = pacc + (size_t)2 * B_ * N_ * OD;      // 2*16384 f
    unsigned char* packT =
        (unsigned char*)(psum + (size_t)2 * B_ * N_ * H_);  // 512 KB

    pack_kernel<<<1024, 256, 0, stream>>>(adj, packT);
    proj_kernel<<<512, 256, 0, stream>>>(x, Wl, bl, Wr, br, att, xl, xr, dlT, drT);
    attn_kernel<<<2048, 256, 0, stream>>>(packT, att, xl, xr, dlT, drT, pacc, psum);
    combine_kernel<<<1024, 256, 0, stream>>>(pacc, psum, bias, out);
}

// Round 15
// 130.576 us; speedup vs baseline: 1.0121x; 1.0121x over previous
//
#include <hip/hip_runtime.h>
#include <hip/hip_bf16.h>

#define B_   8
#define N_   512
#define IND  256
#define H_   4
#define PH   32
#define OD   128   // H_*PH
#define TI   4     // targets per block (attn)

typedef float v2f __attribute__((ext_vector_type(2)));

// leaky 0.4 * log2(e), and 0.6 * log2(e): logits in log2 domain -> v_exp_f32.
#define ATT_SCALE 0.5770780163555854f
#define DLR_SCALE 0.8656170245333781f

template <int PAT>
__device__ __forceinline__ float dpp_add(float x) {
    int yi = __builtin_amdgcn_mov_dpp(__float_as_int(x), PAT, 0xF, 0xF, true);
    return x + __int_as_float(yi);
}

__device__ __forceinline__ float fast_exp2(float x) {
#if __has_builtin(__builtin_amdgcn_exp2f)
    return __builtin_amdgcn_exp2f(x);
#else
    return exp2f(x);
#endif
}

// Packed fp32 FMA / ADD forced as single VOP3P instructions (r9 post-mortem).
__device__ __forceinline__ void pk_fma(v2f& d, v2f a, v2f b) {
    asm("v_pk_fma_f32 %0, %1, %2, %0" : "+v"(d) : "v"(a), "v"(b));
}
__device__ __forceinline__ v2f pk_add(v2f a, v2f b) {
    v2f d;
    asm("v_pk_add_f32 %0, %1, %2" : "=v"(d) : "v"(a), "v"(b));
    return d;
}

// ---------------------------------------------------------------------------
// Kernel 0: pack adjacency into j-CONTIGUOUS nibble table, diagonal folded.
// packT[(b*128 + iq)*512 + j] = 4 mask bits for targets i = iq*4..iq*4+3.
// (r14-verified) j-contiguous bytes -> 1 cache-line segment per u in attn.
// ---------------------------------------------------------------------------
__global__ __launch_bounds__(256) void pack_kernel(
    const int* __restrict__ adj, unsigned char* __restrict__ packT)
{
    const int t = threadIdx.x;
    const int lane = t & 63;
    const int r = blockIdx.x * 4 + (t >> 6);     // (b*N + j)
    const int j = r & (N_ - 1);
    const int b = r >> 9;
    const int* row = adj + (size_t)r * N_;
    #pragma unroll
    for (int k = 0; k < 8; ++k) {
        const int i = k * 64 + lane;
        int a = row[i];
        unsigned long long m = __ballot(a != 0 || i == j);
        if (lane < 16) {
            const int iq = k * 16 + lane;
            packT[((size_t)(b * 128 + iq)) * N_ + j] =
                (unsigned char)((m >> (lane * 4)) & 15ull);
        }
    }
}

// ---------------------------------------------------------------------------
// Kernel 1: xl = x@Wl + bl ; xr = x@Wr + br  plus pre-scaled rank-1 parts,
// stored TRANSPOSED: dlT/drT[(b*H + h)*N + n]  (j-contiguous for attn).
// grid 512, block 256; 8 rows per block. (r14-verified)
// ---------------------------------------------------------------------------
__global__ __launch_bounds__(256, 2) void proj_kernel(
    const float* __restrict__ x,
    const float* __restrict__ Wl, const float* __restrict__ bl,
    const float* __restrict__ Wr, const float* __restrict__ br,
    const float* __restrict__ att,
    float* __restrict__ xl, float* __restrict__ xr,
    float* __restrict__ dlT, float* __restrict__ drT)
{
    __shared__ float xs[8 * IND];
    const int t = threadIdx.x;
    const int row0 = blockIdx.x * 8;

    const float4* xp4 = (const float4*)(x + (size_t)row0 * IND);
    float4* xs4 = (float4*)xs;
    #pragma unroll
    for (int k = 0; k < 2; ++k)
        xs4[t + k * 256] = xp4[t + k * 256];
    __syncthreads();

    const int which = t >> 7;
    const int rg = (t >> 6) & 1;
    const int og = t & 63;
    const int o0 = og * 2;
    const int r0 = rg * 4;
    const float* W  = which ? Wr : Wl;
    const float* bb = which ? br : bl;

    float acc0[4], acc1[4];
    #pragma unroll
    for (int r = 0; r < 4; ++r) { acc0[r] = 0.f; acc1[r] = 0.f; }

    for (int k = 0; k < IND; k += 4) {
        float wf0[4], wf1[4];
        #pragma unroll
        for (int kk = 0; kk < 4; ++kk) {
            float2 wv = *(const float2*)(W + (size_t)(k + kk) * OD + o0);
            wf0[kk] = wv.x;
            wf1[kk] = wv.y;
        }
        float xv[4][4];
        #pragma unroll
        for (int r = 0; r < 4; ++r)
            *(float4*)(xv[r]) = *(const float4*)(&xs[(r0 + r) * IND + k]);
        #pragma unroll
        for (int kk = 0; kk < 4; ++kk)
            #pragma unroll
            for (int r = 0; r < 4; ++r) {
                acc0[r] = fmaf(xv[r][kk], wf0[kk], acc0[r]);
                acc1[r] = fmaf(xv[r][kk], wf1[kk], acc1[r]);
            }
    }

    const float bv0 = bb[o0];
    const float bv1 = bb[o0 + 1];
    const float a0 = att[o0];
    const float a1 = att[o0 + 1];
    float* dst = which ? xr : xl;
    float* dp  = which ? drT : dlT;
    float dcon[4];
    #pragma unroll
    for (int r = 0; r < 4; ++r) {
        float y0 = acc0[r] + bv0;
        float y1 = acc1[r] + bv1;
        *(float2*)(&dst[(size_t)(row0 + r0 + r) * OD + o0]) = make_float2(y0, y1);
        dcon[r] = fmaf(a0, y0, a1 * y1);
    }
    #pragma unroll
    for (int m = 1; m < 16; m <<= 1) {
        #pragma unroll
        for (int r = 0; r < 4; ++r)
            dcon[r] += __shfl_xor(dcon[r], m);
    }
    if ((og & 15) == 0) {
        const int h = og >> 4;
        #pragma unroll
        for (int r = 0; r < 4; ++r) {
            const int n = row0 + r0 + r;
            const int bb2 = n >> 9, nn = n & (N_ - 1);
            dp[((size_t)(bb2 * H_ + h)) * N_ + nn] = DLR_SCALE * dcon[r];
        }
    }
}

// ---------------------------------------------------------------------------
// Kernel 2: masked-softmax attention. Single kernel (r14: j-split's extra
// dispatches cost more than they saved). ZERO LDS, ZERO BARRIERS.
// grid 1024 (= B*N/TI), block 256, TI=4 (r11: TI=2 doubles loads).
// thread: cq = t&3, js = (t>>2)&15, h = t>>6.
// Mask: 1-byte j-contiguous nibble (1 segment/u); dl: j-contiguous
// (1 segment/u) -- per-u cache-line segments 52 -> 34 vs r12.
// Prefetch depth 2 (rotating slots) to cover L2 latency at 4 blocks/CU.
// e2: pk_add + scalar fma with folded |.|; PV: v_pk_fma_f32; log2-domain
// logits; epilogue: pure-shuffle reduce-scatter (r12-verified).
// ---------------------------------------------------------------------------
__global__ __launch_bounds__(256, 3) void attn_kernel(
    const unsigned char* __restrict__ packT,
    const float* __restrict__ att, const float* __restrict__ bias,
    const float* __restrict__ xl, const float* __restrict__ xr,
    const float* __restrict__ dlT, const float* __restrict__ drT,
    float* __restrict__ out)
{
    const int t = threadIdx.x;
    const int b  = blockIdx.x >> 7;
    const int i0 = (blockIdx.x & 127) * TI;
    const int cq = t & 3;
    const int js = (t >> 2) & 15;
    const int h  = t >> 6;
    const int cbase = h * PH + cq * 8;

    float atS[8];
    {
        const float* ap = att + cbase;
        float4 a0 = *(const float4*)(ap);
        float4 a1 = *(const float4*)(ap + 4);
        atS[0] = ATT_SCALE * a0.x; atS[1] = ATT_SCALE * a0.y;
        atS[2] = ATT_SCALE * a0.z; atS[3] = ATT_SCALE * a0.w;
        atS[4] = ATT_SCALE * a1.x; atS[5] = ATT_SCALE * a1.y;
        atS[6] = ATT_SCALE * a1.z; atS[7] = ATT_SCALE * a1.w;
    }
    v2f xr2[TI][4];
    float drv[TI];
    #pragma unroll
    for (int il = 0; il < TI; ++il) {
        const float* xp = xr + ((size_t)(b * N_ + i0 + il)) * OD + cbase;
        float4 r0 = *(const float4*)(xp);
        float4 r1 = *(const float4*)(xp + 4);
        xr2[il][0] = (v2f){r0.x, r0.y};
        xr2[il][1] = (v2f){r0.z, r0.w};
        xr2[il][2] = (v2f){r1.x, r1.y};
        xr2[il][3] = (v2f){r1.z, r1.w};
        drv[il] = drT[((size_t)(b * H_ + h)) * N_ + i0 + il];  // pre-scaled
    }

    v2f acc[TI][4];
    float sumw[TI];
    #pragma unroll
    for (int il = 0; il < TI; ++il) {
        sumw[il] = 0.f;
        #pragma unroll
        for (int m = 0; m < 4; ++m) acc[il][m] = (v2f){0.f, 0.f};
    }

    // j-loop, j = u*16 + js, u = 0..31, prefetch depth 2.
    const float*         xlp = xl + ((size_t)(b * N_ + js)) * OD + cbase;
    const unsigned char* ptp = packT + ((size_t)(b * 128 + (i0 >> 2))) * N_ + js;
    const float*         dlp = dlT + ((size_t)(b * H_ + h)) * N_ + js;

    float4   va0 = *(const float4*)(xlp);
    float4   vb0 = *(const float4*)(xlp + 4);
    unsigned pj0 = *ptp;
    float    dj0 = *dlp;
    xlp += 16 * OD; ptp += 16; dlp += 16;
    float4   va1 = *(const float4*)(xlp);
    float4   vb1 = *(const float4*)(xlp + 4);
    unsigned pj1 = *ptp;
    float    dj1 = *dlp;

    #pragma unroll 2
    for (int u = 0; u < 32; ++u) {
        float4   wa = va0, wb = vb0;
        unsigned wp = pj0;
        float    wd = dj0;
        va0 = va1; vb0 = vb1; pj0 = pj1; dj0 = dj1;
        if (u < 30) {
            xlp += 16 * OD; ptp += 16; dlp += 16;
            va1 = *(const float4*)(xlp);
            vb1 = *(const float4*)(xlp + 4);
            pj1 = *ptp;
            dj1 = *dlp;
        }
        v2f p0 = (v2f){wa.x, wa.y}, p1 = (v2f){wa.z, wa.w};
        v2f p2 = (v2f){wb.x, wb.y}, p3 = (v2f){wb.z, wb.w};
        #pragma unroll
        for (int il = 0; il < TI; ++il) {
            float e2a = 0.f, e2b = 0.f;
            v2f sv;
            sv = pk_add(xr2[il][0], p0);
            e2a = fmaf(atS[0], __builtin_fabsf(sv.x), e2a);
            e2b = fmaf(atS[1], __builtin_fabsf(sv.y), e2b);
            sv = pk_add(xr2[il][1], p1);
            e2a = fmaf(atS[2], __builtin_fabsf(sv.x), e2a);
            e2b = fmaf(atS[3], __builtin_fabsf(sv.y), e2b);
            sv = pk_add(xr2[il][2], p2);
            e2a = fmaf(atS[4], __builtin_fabsf(sv.x), e2a);
            e2b = fmaf(atS[5], __builtin_fabsf(sv.y), e2b);
            sv = pk_add(xr2[il][3], p3);
            e2a = fmaf(atS[6], __builtin_fabsf(sv.x), e2a);
            e2b = fmaf(atS[7], __builtin_fabsf(sv.y), e2b);
            float eh = e2a + e2b;
            eh = dpp_add<0xB1>(eh);          // + lane^1 (quad_perm 1,0,3,2)
            eh = dpp_add<0x4E>(eh);          // + lane^2 (quad_perm 2,3,0,1)
            float e = (wd + drv[il]) + eh;   // full log2-domain logit
            float ex = fast_exp2(e);
            float w = (wp & (1u << il)) ? ex : 0.f;   // diagonal pre-folded
            sumw[il] += w;
            v2f ws = (v2f){w, w};
            pk_fma(acc[il][0], ws, p0);
            pk_fma(acc[il][1], ws, p1);
            pk_fma(acc[il][2], ws, p2);
            pk_fma(acc[il][3], ws, p3);
        }
    }

    // ---- epilogue: pure-shuffle reduce-scatter over js (r12-verified) ----
    #pragma unroll
    for (int il = 0; il < TI; ++il) {
        sumw[il] += __shfl_xor(sumw[il], 4);
        sumw[il] += __shfl_xor(sumw[il], 8);
        sumw[il] += __shfl_xor(sumw[il], 16);
        sumw[il] += __shfl_xor(sumw[il], 32);
    }

    float accf[32];
    #pragma unroll
    for (int il = 0; il < TI; ++il)
        #pragma unroll
        for (int m = 0; m < 4; ++m) {
            accf[il * 8 + 2 * m]     = acc[il][m].x;
            accf[il * 8 + 2 * m + 1] = acc[il][m].y;
        }

    float r16[16];
    {
        const bool hi = (js & 1) != 0;
        #pragma unroll
        for (int m = 0; m < 16; ++m) {
            float send = hi ? accf[m] : accf[16 + m];
            float keep = hi ? accf[16 + m] : accf[m];
            r16[m] = keep + __shfl_xor(send, 4);
        }
    }
    float r8[8];
    {
        const bool hi = (js & 2) != 0;
        #pragma unroll
        for (int m = 0; m < 8; ++m) {
            float send = hi ? r16[m] : r16[8 + m];
            float keep = hi ? r16[8 + m] : r16[m];
            r8[m] = keep + __shfl_xor(send, 8);
        }
    }
    float r4[4];
    {
        const bool hi = (js & 4) != 0;
        #pragma unroll
        for (int m = 0; m < 4; ++m) {
            float send = hi ? r8[m] : r8[4 + m];
            float keep = hi ? r8[4 + m] : r8[m];
            r4[m] = keep + __shfl_xor(send, 16);
        }
    }
    float r2[2];
    {
        const bool hi = (js & 8) != 0;
        #pragma unroll
        for (int m = 0; m < 2; ++m) {
            float send = hi ? r4[m] : r4[2 + m];
            float keep = hi ? r4[2 + m] : r4[m];
            r2[m] = keep + __shfl_xor(send, 32);
        }
    }

    const int il = ((js & 1) << 1) | ((js >> 1) & 1);
    const int coff = ((js >> 2) & 1) * 4 + ((js >> 3) & 1) * 2;
    const int c = cbase + coff;
    const float sw0 = (js & 1) ? ((js & 2) ? sumw[3] : sumw[2])
                               : ((js & 2) ? sumw[1] : sumw[0]);
    const float inv = 1.f / sw0;
    float* op = out + ((size_t)(b * N_ + i0 + il)) * OD;
    *(float2*)(&op[c]) = make_float2(fmaf(r2[0], inv, bias[c]),
                                     fmaf(r2[1], inv, bias[c + 1]));
}

extern "C" void kernel_launch(void* const* d_in, const int* in_sizes, int n_in,
                              void* d_out, int out_size, void* d_ws, size_t ws_size,
                              hipStream_t stream) {
    const float* x    = (const float*)d_in[0];
    const int*   adj  = (const int*)d_in[1];
    const float* Wl   = (const float*)d_in[2];
    const float* bl   = (const float*)d_in[3];
    const float* Wr   = (const float*)d_in[4];
    const float* br   = (const float*)d_in[5];
    const float* att  = (const float*)d_in[6];
    const float* bias = (const float*)d_in[7];
    float* out = (float*)d_out;

    float* ws = (float*)d_ws;
    float* xl  = ws;                                  // 524288 f
    float* xr  = xl + (size_t)B_ * N_ * OD;           // 524288 f
    float* dlT = xr + (size_t)B_ * N_ * OD;           // 16384 f
    float* drT = dlT + (size_t)B_ * N_ * H_;          // 16384 f
    unsigned char* packT =
        (unsigned char*)(drT + (size_t)B_ * N_ * H_); // 512 KB

    pack_kernel<<<1024, 256, 0, stream>>>(adj, packT);
    proj_kernel<<<512, 256, 0, stream>>>(x, Wl, bl, Wr, br, att, xl, xr, dlT, drT);
    attn_kernel<<<1024, 256, 0, stream>>>(packT, att, bias, xl, xr, dlT, drT, out);
}